// Round 3
// baseline (161.430 us; speedup 1.0000x reference)
//
#include <hip/hip_runtime.h>

// B=4, HG=WG=32 -> 1024 tokens/batch, 4096 total; D=768, NH=12, HD=64, K=7 (49 neighbors)

typedef __bf16 bf16x8 __attribute__((ext_vector_type(8)));
typedef short s16x4 __attribute__((ext_vector_type(4)));
typedef float f32x4 __attribute__((ext_vector_type(4)));

__device__ __forceinline__ unsigned short f2bf(float f) {
  unsigned u = __float_as_uint(f);
  u += 0x7fffu + ((u >> 16) & 1u);   // RNE
  return (unsigned short)(u >> 16);
}

template <typename T>
__device__ __forceinline__ void gld_lds16(const T* g, T* l) {
  __builtin_amdgcn_global_load_lds((const __attribute__((address_space(1))) void*)g,
                                   (__attribute__((address_space(3))) void*)l, 16, 0, 0);
}

// ---------------- fp32 -> bf16 conversion of x, qkv_w, proj_w ----------------
__global__ void cvt_kernel(const float* __restrict__ x, const float* __restrict__ w1,
                           const float* __restrict__ w2, unsigned short* __restrict__ xo,
                           unsigned short* __restrict__ w1o, unsigned short* __restrict__ w2o) {
  const int n1 = 4096 * 768 / 4;
  const int n2 = 2304 * 768 / 4;
  const int n3 = 768 * 768 / 4;
  int i = blockIdx.x * 256 + threadIdx.x;
  float4 v;
  unsigned short* dst;
  int o;
  if (i < n1) {
    o = i; v = ((const float4*)x)[o]; dst = xo;
  } else if (i < n1 + n2) {
    o = i - n1; v = ((const float4*)w1)[o]; dst = w1o;
  } else if (i < n1 + n2 + n3) {
    o = i - n1 - n2; v = ((const float4*)w2)[o]; dst = w2o;
  } else {
    return;
  }
  ushort4 r;
  r.x = f2bf(v.x); r.y = f2bf(v.y); r.z = f2bf(v.z); r.w = f2bf(v.w);
  ((ushort4*)dst)[o] = r;
}

// ---------------- bf16 GEMM, C = A * B^T + bias ----------------
// MODE 0 (qkv): BM=BN=128, grid (18,32). Q cols scaled, token-major out; V transposed.
// MODE 1 (proj): BM=BN=64, grid (12,64)=768 blocks -> 3 blocks/CU co-resident.
// Double-buffered LDS + in-loop prefetch; XOR chunk swizzle both-sides (rule 21);
// XCD 2D-rectangle swizzle keeps per-XCD L2 working set under 4 MiB.
template <int MODE, int BM, int BN>
__global__ __launch_bounds__(256) void gemm_bt(const unsigned short* __restrict__ A,
                                               const unsigned short* __restrict__ Bm,
                                               const float* __restrict__ bias,
                                               unsigned short* __restrict__ obf,
                                               unsigned short* __restrict__ vtout,
                                               float* __restrict__ of32,
                                               int M, int N, int Kd) {
  constexpr int RA = BM / 64, RB = BN / 64;   // gld rounds per tile
  constexpr int MI = BM / 32, NI = BN / 32;   // 16x16 frags per wave
  __shared__ __align__(16) unsigned short sA[2][BM * 32];
  __shared__ __align__(16) unsigned short sB[2][BN * 32];
  const int tid = threadIdx.x;
  const int lane = tid & 63;
  const int wv = tid >> 6;

  // XCD rectangles: qkv (18,32): HX=9, HY=8 -> 3.3 MB/XCD. proj (12,64): HX=6, HY=16.
  constexpr int HX = (MODE == 0) ? 9 : 6;
  constexpr int HY = (MODE == 0) ? 8 : 16;
  const int lin = blockIdx.y * gridDim.x + blockIdx.x;
  const int xcd = lin & 7, rrr = lin >> 3;
  const int bx = (xcd & 1) * HX + rrr % HX;
  const int by = (xcd >> 1) * HY + rrr / HX;
  const int m0 = by * BM, n0 = bx * BN;

  const int wrow = (wv >> 1) * (BM / 2), wcol = (wv & 1) * (BN / 2);
  const int lr = lane & 15, lq = lane >> 4;
  // read-side swizzled chunk: physical chunk = lq ^ ((row>>1)&3); row = 16m+lr
  const int rchunk = (lq ^ ((lr >> 1) & 3)) * 8;

  f32x4 acc[MI][NI] = {};

  // source-side chunk swizzle matches read side (both-sides-or-neither).
  const int schunk = ((tid & 3) ^ ((tid >> 3) & 3)) * 8;
  const unsigned short* gA = A + (size_t)(m0 + (tid >> 2)) * Kd + schunk;
  const unsigned short* gB = Bm + (size_t)(n0 + (tid >> 2)) * Kd + schunk;

  // prologue: stage k-tile 0 into buffer 0
#pragma unroll
  for (int r = 0; r < RA; ++r) gld_lds16(gA + (size_t)(r * 64) * Kd, &sA[0][r * 2048 + tid * 8]);
#pragma unroll
  for (int r = 0; r < RB; ++r) gld_lds16(gB + (size_t)(r * 64) * Kd, &sB[0][r * 2048 + tid * 8]);
  __syncthreads();

  int cur = 0;
  for (int k0 = 0; k0 < Kd; k0 += 32) {
    const int nxt = k0 + 32;
    if (nxt < Kd) {  // issue next-tile stage BEFORE consuming current tile
      unsigned short* dA = sA[cur ^ 1];
      unsigned short* dB = sB[cur ^ 1];
#pragma unroll
      for (int r = 0; r < RA; ++r) gld_lds16(gA + (size_t)(r * 64) * Kd + nxt, dA + r * 2048 + tid * 8);
#pragma unroll
      for (int r = 0; r < RB; ++r) gld_lds16(gB + (size_t)(r * 64) * Kd + nxt, dB + r * 2048 + tid * 8);
    }
    const unsigned short* cA = sA[cur];
    const unsigned short* cB = sB[cur];
    bf16x8 af[MI], bfr[NI];
#pragma unroll
    for (int t = 0; t < MI; ++t) af[t] = *(const bf16x8*)(cA + (wrow + t * 16 + lr) * 32 + rchunk);
#pragma unroll
    for (int t = 0; t < NI; ++t) bfr[t] = *(const bf16x8*)(cB + (wcol + t * 16 + lr) * 32 + rchunk);
#pragma unroll
    for (int im = 0; im < MI; ++im)
#pragma unroll
      for (int in = 0; in < NI; ++in)
        acc[im][in] = __builtin_amdgcn_mfma_f32_16x16x32_bf16(af[im], bfr[in], acc[im][in], 0, 0, 0);
    __syncthreads();  // drains vmcnt (prefetch) + lgkm; one barrier per k-step
    cur ^= 1;
  }

  if (MODE == 0) {
    const int sidx = n0 / 768;  // block-uniform (768 % BN == 0)
    if (sidx == 2) {
      // V -> transposed vt[(hh*64+dd)*4096 + token]
#pragma unroll
      for (int im = 0; im < MI; ++im) {
#pragma unroll
        for (int in = 0; in < NI; ++in) {
          int gn = n0 + wcol + in * 16 + lr;
          int rem = gn - 1536;
          int hh = rem >> 6, dd = gn & 63;
          float bsv = bias[gn];
          int gm0 = m0 + wrow + im * 16 + lq * 4;
          ushort4 pk;
          pk.x = f2bf(acc[im][in][0] + bsv);
          pk.y = f2bf(acc[im][in][1] + bsv);
          pk.z = f2bf(acc[im][in][2] + bsv);
          pk.w = f2bf(acc[im][in][3] + bsv);
          *(ushort4*)(vtout + (size_t)(hh * 64 + dd) * 4096 + gm0) = pk;
        }
      }
    } else {
      const float scale = (sidx == 0) ? 0.18033688f : 1.0f;  // 0.125 * log2(e) for Q
#pragma unroll
      for (int im = 0; im < MI; ++im) {
#pragma unroll
        for (int in = 0; in < NI; ++in) {
          int gn = n0 + wcol + in * 16 + lr;
          int rem = gn - sidx * 768;
          int hh = rem >> 6, dd = gn & 63;
          float bsv = bias[gn];
#pragma unroll
          for (int r = 0; r < 4; ++r) {
            int gm = m0 + wrow + im * 16 + lq * 4 + r;
            float val = (acc[im][in][r] + bsv) * scale;
            obf[((size_t)(sidx * 12 + hh) * 4096 + gm) * 64 + dd] = f2bf(val);
          }
        }
      }
    }
  } else {
#pragma unroll
    for (int im = 0; im < MI; ++im) {
#pragma unroll
      for (int in = 0; in < NI; ++in) {
        int gn = n0 + wcol + in * 16 + lr;
        float bsv = bias[gn];
#pragma unroll
        for (int r = 0; r < 4; ++r) {
          int gm = m0 + wrow + im * 16 + lq * 4 + r;
          of32[(size_t)gm * N + gn] = acc[im][in][r] + bsv;
        }
      }
    }
  }
}

// ---------------- neighborhood attention (MFMA, ZERO-LDS) ----------------
// Per (head,batch) K and V are 128 KB each -> L1/L2-resident. Staging them in
// LDS was pure overhead (m169 precedent): this version has NO LDS, NO barriers,
// NO staging registers — 4 fully independent waves per block.
//   QK^T: mfma_f32_16x16x32_bf16, A=K-frag / B=Q-frag loaded straight from
//     global: x32 fragment layout is per-lane 16B contiguous ([row=lane&15]
//     [k=(lane>>4)*8..+7]) -> one dwordx4 per fragment, one full 128B line per
//     K-row. C-layout (col=lane&15=q, row=lg*4+r=token) identical to the x16
//     path, so mask/softmax/register-direct-P are unchanged.
//   PV: mfma_16x16x16bf16_1k (P stays in registers); V read straight from the
//     transposed vt[d][4096] layout, 8B contiguous per lane, rows L1-resident.
__global__ __launch_bounds__(256) void natten_kernel(const unsigned short* __restrict__ qkvt,
                                                     unsigned short* __restrict__ aout) {
  const int h = blockIdx.x, ip = blockIdx.y, b = blockIdx.z;
  const int i0 = ip * 2;
  const int tid = threadIdx.x, lane = tid & 63, wv = tid >> 6;
  const int lg = lane >> 4, lm = lane & 15;
  const int gb = b * 1024;
  const unsigned short* Qg = qkvt + ((size_t)h * 4096 + gb + i0 * 32) * 64;
  const unsigned short* Kg = qkvt + ((size_t)(12 + h) * 4096 + gb) * 64;
  const unsigned short* Vg = qkvt + (size_t)24 * 4096 * 64 + (size_t)h * 64 * 4096 + gb;

  const int row_sel = wv >> 1;   // which query grid-row of the pair
  const int jhalf = wv & 1;      // which 16-query column half
  const int i = i0 + row_sel;
  int si_w = i - 3; si_w = si_w < 0 ? 0 : si_w; if (si_w > 25) si_w = 25;
  const int j = jhalf * 16 + lm;
  int sj = j - 3; sj = sj < 0 ? 0 : sj; if (sj > 25) sj = 25;

  // column mask: token col c depends only on (tile parity, lg, reg)
  float madd[2][4];
#pragma unroll
  for (int p = 0; p < 2; ++p)
#pragma unroll
    for (int r = 0; r < 4; ++r) {
      int c = p * 16 + lg * 4 + r;
      madd[p][r] = (c >= sj && c <= sj + 6) ? 0.f : -1e30f;
    }

  // Q B-fragments (x32): lane holds Q[q=jhalf*16+lm][d = ks*32 + lg*8 .. +7]
  bf16x8 qf[2];
  const unsigned short* qrowp = Qg + (row_sel * 32 + j) * 64;
#pragma unroll
  for (int ks = 0; ks < 2; ++ks)
    qf[ks] = *(const bf16x8*)(qrowp + ks * 32 + lg * 8);

  // S^T = K · Q^T  (A-frag: lane holds K[tok = 16*tt + lm][d = ks*32 + lg*8 ..+7])
  const unsigned short* Kw = Kg + (size_t)(si_w * 32) * 64;
  f32x4 accS[14];
#pragma unroll
  for (int tt = 0; tt < 14; ++tt) {
    f32x4 a = {0.f, 0.f, 0.f, 0.f};
    const unsigned short* kr = Kw + (tt * 16 + lm) * 64;
#pragma unroll
    for (int ks = 0; ks < 2; ++ks) {
      bf16x8 kf = *(const bf16x8*)(kr + ks * 32 + lg * 8);
      a = __builtin_amdgcn_mfma_f32_16x16x32_bf16(kf, qf[ks], a, 0, 0, 0);
    }
    accS[tt] = a;
  }

  // masked softmax (base-2; scale pre-folded into Q)
  float mx = -3e38f;
#pragma unroll
  for (int tt = 0; tt < 14; ++tt)
#pragma unroll
    for (int r = 0; r < 4; ++r) {
      float v = accS[tt][r] + madd[tt & 1][r];
      accS[tt][r] = v;
      mx = fmaxf(mx, v);
    }
  mx = fmaxf(mx, __shfl_xor(mx, 16, 64));
  mx = fmaxf(mx, __shfl_xor(mx, 32, 64));
  float sum = 0.f;
#pragma unroll
  for (int tt = 0; tt < 14; ++tt)
#pragma unroll
    for (int r = 0; r < 4; ++r) {
      float p = exp2f(accS[tt][r] - mx);
      accS[tt][r] = p;
      sum += p;
    }
  sum += __shfl_xor(sum, 16, 64);
  sum += __shfl_xor(sum, 32, 64);
  const float inv = 1.f / sum;

  // P fp32 -> bf16 A-fragments (register-direct)
  s16x4 pf[14];
#pragma unroll
  for (int tt = 0; tt < 14; ++tt) {
    union { unsigned u[2]; s16x4 v; } pk;
    pk.u[0] = ((unsigned)f2bf(accS[tt][1]) << 16) | f2bf(accS[tt][0]);
    pk.u[1] = ((unsigned)f2bf(accS[tt][3]) << 16) | f2bf(accS[tt][2]);
    pf[tt] = pk.v;
  }

  // O = P · V   (B-frag: lane holds V[tok = 16*tt + lg*4 ..+3][d = nt*16 + lm])
  const unsigned short* Vw = Vg + si_w * 32;
  f32x4 accO[4] = {};
#pragma unroll
  for (int tt = 0; tt < 14; ++tt) {
    const int tok4 = tt * 16 + lg * 4;
#pragma unroll
    for (int nt = 0; nt < 4; ++nt) {
      const int d = nt * 16 + lm;
      s16x4 vf = *(const s16x4*)(Vw + (size_t)d * 4096 + tok4);
      accO[nt] = __builtin_amdgcn_mfma_f32_16x16x16bf16_1k(pf[tt], vf, accO[nt], 0, 0, 0);
    }
  }

  // 1/sum per output row (O C-layout row = q = lg*4+reg)
  float invr[4];
#pragma unroll
  for (int r = 0; r < 4; ++r) invr[r] = __shfl(inv, lg * 4 + r, 64);

  const int tokbase = gb + i * 32 + jhalf * 16;
#pragma unroll
  for (int nt = 0; nt < 4; ++nt)
#pragma unroll
    for (int r = 0; r < 4; ++r) {
      int tok = tokbase + lg * 4 + r;
      aout[(size_t)tok * 768 + h * 64 + nt * 16 + lm] = f2bf(accO[nt][r] * invr[r]);
    }
}

// ---------------- launch ----------------
extern "C" void kernel_launch(void* const* d_in, const int* in_sizes, int n_in,
                              void* d_out, int out_size, void* d_ws, size_t ws_size,
                              hipStream_t stream) {
  const float* x      = (const float*)d_in[0];
  const float* qkv_w  = (const float*)d_in[1];
  const float* qkv_b  = (const float*)d_in[2];
  const float* proj_w = (const float*)d_in[3];
  const float* proj_b = (const float*)d_in[4];
  char* ws = (char*)d_ws;

  unsigned short* xb    = (unsigned short*)(ws);                 // 4096*768 bf16
  unsigned short* wqkv  = (unsigned short*)(ws + 6291456);       // 2304*768 bf16
  unsigned short* wproj = (unsigned short*)(ws + 9830400);       // 768*768 bf16
  unsigned short* qkvt  = (unsigned short*)(ws + 11010048);      // Q,K token-major + Vt
  unsigned short* attnb = (unsigned short*)(ws + 29884416);      // 4096*768 bf16
  unsigned short* vt    = qkvt + (size_t)24 * 4096 * 64;         // V transposed [12][64][4096]
  float* out = (float*)d_out;

  cvt_kernel<<<5376, 256, 0, stream>>>(x, qkv_w, proj_w, xb, wqkv, wproj);
  gemm_bt<0, 128, 128><<<dim3(18, 32), 256, 0, stream>>>(xb, wqkv, qkv_b, qkvt, vt, nullptr, 4096, 2304, 768);
  natten_kernel<<<dim3(12, 16, 4), 256, 0, stream>>>(qkvt, attnb);
  gemm_bt<1, 64, 64><<<dim3(12, 64), 256, 0, stream>>>(attnb, wproj, proj_b, nullptr, nullptr, out, 4096, 768, 768);
}

// Round 4
// 135.840 us; speedup vs baseline: 1.1884x; 1.1884x over previous
//
#include <hip/hip_runtime.h>

// B=4, HG=WG=32 -> 1024 tokens/batch, 4096 total; D=768, NH=12, HD=64, K=7 (49 neighbors)

typedef __bf16 bf16x8 __attribute__((ext_vector_type(8)));
typedef short s16x4 __attribute__((ext_vector_type(4)));
typedef float f32x4 __attribute__((ext_vector_type(4)));

__device__ __forceinline__ unsigned short f2bf(float f) {
  unsigned u = __float_as_uint(f);
  u += 0x7fffu + ((u >> 16) & 1u);   // RNE
  return (unsigned short)(u >> 16);
}

template <typename T>
__device__ __forceinline__ void gld_lds16(const T* g, T* l) {
  __builtin_amdgcn_global_load_lds((const __attribute__((address_space(1))) void*)g,
                                   (__attribute__((address_space(3))) void*)l, 16, 0, 0);
}

// ---------------- fp32 -> bf16 conversion of x, qkv_w, proj_w ----------------
__global__ void cvt_kernel(const float* __restrict__ x, const float* __restrict__ w1,
                           const float* __restrict__ w2, unsigned short* __restrict__ xo,
                           unsigned short* __restrict__ w1o, unsigned short* __restrict__ w2o) {
  const int n1 = 4096 * 768 / 4;
  const int n2 = 2304 * 768 / 4;
  const int n3 = 768 * 768 / 4;
  int i = blockIdx.x * 256 + threadIdx.x;
  float4 v;
  unsigned short* dst;
  int o;
  if (i < n1) {
    o = i; v = ((const float4*)x)[o]; dst = xo;
  } else if (i < n1 + n2) {
    o = i - n1; v = ((const float4*)w1)[o]; dst = w1o;
  } else if (i < n1 + n2 + n3) {
    o = i - n1 - n2; v = ((const float4*)w2)[o]; dst = w2o;
  } else {
    return;
  }
  ushort4 r;
  r.x = f2bf(v.x); r.y = f2bf(v.y); r.z = f2bf(v.z); r.w = f2bf(v.w);
  ((ushort4*)dst)[o] = r;
}

// ---------------- bf16 GEMM, C = A * B^T + bias ----------------
// Depth-2 software pipeline (T4 counted waits): 3 LDS buffers; step k reads
// tile k, issues stage of tile k+2, then waits vmcnt(L) (tile k+1 landed,
// tile k+2 still in flight) + lgkmcnt(0) (my ds_reads drained -> next step's
// overwrite of buf[k%3] is race-free) + raw s_barrier. Unlike __syncthreads
// (vmcnt(0) drain), prefetched loads get ~1.7 steps of latency slack.
// MODE 0 (qkv): BM=BN=128. MODE 1 (proj): BM=BN=64, 768 blocks = 3/CU.
// XOR chunk swizzle both-sides (rule 21); XCD 2D-rectangle block swizzle.
template <int MODE, int BM, int BN>
__global__ __launch_bounds__(256) void gemm_bt(const unsigned short* __restrict__ A,
                                               const unsigned short* __restrict__ Bm,
                                               const float* __restrict__ bias,
                                               unsigned short* __restrict__ obf,
                                               unsigned short* __restrict__ vtout,
                                               float* __restrict__ of32,
                                               int M, int N, int Kd) {
  constexpr int RA = BM / 64, RB = BN / 64;   // gld rounds per tile
  constexpr int MI = BM / 32, NI = BN / 32;   // 16x16 frags per wave
  constexpr int L = RA + RB;                  // global_load_lds per tile per thread
  __shared__ __align__(16) unsigned short sA[3][BM * 32];
  __shared__ __align__(16) unsigned short sB[3][BN * 32];
  const int tid = threadIdx.x;
  const int lane = tid & 63;
  const int wv = tid >> 6;

  // XCD rectangles: qkv (18,32): HX=9, HY=8 -> 3.3 MB/XCD. proj (12,64): HX=6, HY=16.
  constexpr int HX = (MODE == 0) ? 9 : 6;
  constexpr int HY = (MODE == 0) ? 8 : 16;
  const int lin = blockIdx.y * gridDim.x + blockIdx.x;
  const int xcd = lin & 7, rrr = lin >> 3;
  const int bx = (xcd & 1) * HX + rrr % HX;
  const int by = (xcd >> 1) * HY + rrr / HX;
  const int m0 = by * BM, n0 = bx * BN;

  const int wrow = (wv >> 1) * (BM / 2), wcol = (wv & 1) * (BN / 2);
  const int lr = lane & 15, lq = lane >> 4;
  // read-side swizzled chunk: physical chunk = lq ^ ((row>>1)&3); row = 16m+lr
  const int rchunk = (lq ^ ((lr >> 1) & 3)) * 8;

  f32x4 acc[MI][NI] = {};

  // source-side chunk swizzle matches read side (both-sides-or-neither).
  const int schunk = ((tid & 3) ^ ((tid >> 3) & 3)) * 8;
  const unsigned short* gA = A + (size_t)(m0 + (tid >> 2)) * Kd + schunk;
  const unsigned short* gB = Bm + (size_t)(n0 + (tid >> 2)) * Kd + schunk;

  const int NS = Kd >> 5;  // 32-wide k-steps (24 here)

#define STAGE_TILE(tile, bufidx)                                                          \
  do {                                                                                    \
    const int _off = (tile) * 32;                                                         \
    unsigned short* _dA = sA[(bufidx)];                                                   \
    unsigned short* _dB = sB[(bufidx)];                                                   \
    _Pragma("unroll")                                                                     \
    for (int _r = 0; _r < RA; ++_r)                                                       \
      gld_lds16(gA + (size_t)(_r * 64) * Kd + _off, _dA + _r * 2048 + tid * 8);           \
    _Pragma("unroll")                                                                     \
    for (int _r = 0; _r < RB; ++_r)                                                       \
      gld_lds16(gB + (size_t)(_r * 64) * Kd + _off, _dB + _r * 2048 + tid * 8);           \
  } while (0)

  // prologue: tiles 0 and 1 in flight; wait for tile 0 only.
  STAGE_TILE(0, 0);
  STAGE_TILE(1, 1);
  __builtin_amdgcn_sched_barrier(0);
  if constexpr (L == 4) asm volatile("s_waitcnt vmcnt(4) lgkmcnt(0)" ::: "memory");
  else                  asm volatile("s_waitcnt vmcnt(2) lgkmcnt(0)" ::: "memory");
  __builtin_amdgcn_s_barrier();

  for (int step = 0; step < NS; ++step) {
    const unsigned short* cA = sA[step % 3];
    const unsigned short* cB = sB[step % 3];
    bf16x8 af[MI], bfr[NI];
#pragma unroll
    for (int t = 0; t < MI; ++t) af[t] = *(const bf16x8*)(cA + (wrow + t * 16 + lr) * 32 + rchunk);
#pragma unroll
    for (int t = 0; t < NI; ++t) bfr[t] = *(const bf16x8*)(cB + (wcol + t * 16 + lr) * 32 + rchunk);

    if (step + 2 < NS) STAGE_TILE(step + 2, (step + 2) % 3);  // issue while MFMAs run

#pragma unroll
    for (int im = 0; im < MI; ++im)
#pragma unroll
      for (int in = 0; in < NI; ++in)
        acc[im][in] = __builtin_amdgcn_mfma_f32_16x16x32_bf16(af[im], bfr[in], acc[im][in], 0, 0, 0);

    __builtin_amdgcn_sched_barrier(0);  // pin stage-issues before the counted wait
    if (step < NS - 2) {
      if constexpr (L == 4) asm volatile("s_waitcnt vmcnt(4) lgkmcnt(0)" ::: "memory");
      else                  asm volatile("s_waitcnt vmcnt(2) lgkmcnt(0)" ::: "memory");
    } else {
      asm volatile("s_waitcnt vmcnt(0) lgkmcnt(0)" ::: "memory");
    }
    __builtin_amdgcn_s_barrier();
  }
#undef STAGE_TILE

  if (MODE == 0) {
    const int sidx = n0 / 768;  // block-uniform (768 % BN == 0)
    if (sidx == 2) {
      // V -> transposed vt[(hh*64+dd)*4096 + token]
#pragma unroll
      for (int im = 0; im < MI; ++im) {
#pragma unroll
        for (int in = 0; in < NI; ++in) {
          int gn = n0 + wcol + in * 16 + lr;
          int rem = gn - 1536;
          int hh = rem >> 6, dd = gn & 63;
          float bsv = bias[gn];
          int gm0 = m0 + wrow + im * 16 + lq * 4;
          ushort4 pk;
          pk.x = f2bf(acc[im][in][0] + bsv);
          pk.y = f2bf(acc[im][in][1] + bsv);
          pk.z = f2bf(acc[im][in][2] + bsv);
          pk.w = f2bf(acc[im][in][3] + bsv);
          *(ushort4*)(vtout + (size_t)(hh * 64 + dd) * 4096 + gm0) = pk;
        }
      }
    } else {
      const float scale = (sidx == 0) ? 0.18033688f : 1.0f;  // 0.125 * log2(e) for Q
#pragma unroll
      for (int im = 0; im < MI; ++im) {
#pragma unroll
        for (int in = 0; in < NI; ++in) {
          int gn = n0 + wcol + in * 16 + lr;
          int rem = gn - sidx * 768;
          int hh = rem >> 6, dd = gn & 63;
          float bsv = bias[gn];
#pragma unroll
          for (int r = 0; r < 4; ++r) {
            int gm = m0 + wrow + im * 16 + lq * 4 + r;
            float val = (acc[im][in][r] + bsv) * scale;
            obf[((size_t)(sidx * 12 + hh) * 4096 + gm) * 64 + dd] = f2bf(val);
          }
        }
      }
    }
  } else {
#pragma unroll
    for (int im = 0; im < MI; ++im) {
#pragma unroll
      for (int in = 0; in < NI; ++in) {
        int gn = n0 + wcol + in * 16 + lr;
        float bsv = bias[gn];
#pragma unroll
        for (int r = 0; r < 4; ++r) {
          int gm = m0 + wrow + im * 16 + lq * 4 + r;
          of32[(size_t)gm * N + gn] = acc[im][in][r] + bsv;
        }
      }
    }
  }
}

// ---------------- neighborhood attention (MFMA) ----------------
// REVERTED to the R0/R1 proven version (72 KB LDS, 2 blocks/CU): the R2/R3
// natten restructures regressed (R3 zero-LDS +17 us measured; R2's 64-VGPR
// staging-register variant likely spilled under launch_bounds(256,3)).
// Block = (head, query-row-pair, batch): 64 queries, stages 8 KV grid rows (256 tok).
// S^T = K·Q^T via mfma_16x16x16_bf16: C-layout (col=lane&15=q, row=lg*4+reg=t) is
// EXACTLY the A-operand layout of PV -> P stays in registers.
__global__ __launch_bounds__(256, 2) void natten_kernel(const unsigned short* __restrict__ qkvt,
                                                        unsigned short* __restrict__ aout) {
  __shared__ __align__(16) unsigned short sQ[64 * 64];    //  8 KB
  __shared__ __align__(16) unsigned short sK[256 * 64];   // 32 KB
  __shared__ __align__(16) unsigned short sVt[64 * 256];  // 32 KB
  const int h = blockIdx.x, ip = blockIdx.y, b = blockIdx.z;
  const int i0 = ip * 2;
  const int tid = threadIdx.x, lane = tid & 63, wv = tid >> 6;
  const int lg = lane >> 4, lm = lane & 15;
  int si0 = i0 - 3; si0 = si0 < 0 ? 0 : si0; if (si0 > 25) si0 = 25;
  const int gb = b * 1024;
  const unsigned short* Qg = qkvt + ((size_t)h * 4096 + gb + i0 * 32) * 64;
  const unsigned short* Kg = qkvt + ((size_t)(12 + h) * 4096 + gb) * 64;
  const unsigned short* Vg = qkvt + (size_t)24 * 4096 * 64 + (size_t)h * 64 * 4096 + gb;

  // ---- staging (16B global loads, two 8B LDS writes w/ 4-bit XOR chunk swizzle) ----
#pragma unroll
  for (int it = 0; it < 2; ++it) {  // Q: 64 q x 64 d
    int f = it * 256 + tid;
    int q = f >> 3, c16 = f & 7;
    uint4 v = *(const uint4*)(Qg + q * 64 + c16 * 8);
    int s = q & 15;
    *(uint2*)(sQ + q * 64 + ((((c16 << 1)) ^ s) << 2)) = make_uint2(v.x, v.y);
    *(uint2*)(sQ + q * 64 + ((((c16 << 1) | 1) ^ s) << 2)) = make_uint2(v.z, v.w);
  }
#pragma unroll
  for (int it = 0; it < 8; ++it) {  // K: 256 tok x 64 d
    int f = it * 256 + tid;
    int t = f >> 3, c16 = f & 7;
    int wr = t >> 5, c = t & 31;
    int row = si0 + wr; if (row > 31) row = 31;
    uint4 v = *(const uint4*)(Kg + (row * 32 + c) * 64 + c16 * 8);
    int s = t & 15;
    *(uint2*)(sK + t * 64 + ((((c16 << 1)) ^ s) << 2)) = make_uint2(v.x, v.y);
    *(uint2*)(sK + t * 64 + ((((c16 << 1) | 1) ^ s) << 2)) = make_uint2(v.z, v.w);
  }
#pragma unroll
  for (int it = 0; it < 8; ++it) {  // Vt: 64 d x 256 tok
    int f = it * 256 + tid;
    int d = f >> 5, tc16 = f & 31;
    int wr = tc16 >> 2;
    int row = si0 + wr; if (row > 31) row = 31;
    uint4 v = *(const uint4*)(Vg + (size_t)d * 4096 + row * 32 + (tc16 & 3) * 8);
    int s = d & 15;
    *(uint2*)(sVt + d * 256 + ((((tc16 << 1)) ^ s) << 2)) = make_uint2(v.x, v.y);
    *(uint2*)(sVt + d * 256 + ((((tc16 << 1) | 1) ^ s) << 2)) = make_uint2(v.z, v.w);
  }
  __syncthreads();

  const int row_sel = wv >> 1;
  const int jhalf = wv & 1;
  const int i = i0 + row_sel;
  int si_w = i - 3; si_w = si_w < 0 ? 0 : si_w; if (si_w > 25) si_w = 25;
  const int toff = (si_w - si0) * 32;
  const int j = jhalf * 16 + lm;
  int sj = j - 3; sj = sj < 0 ? 0 : sj; if (sj > 25) sj = 25;

  // column mask: token col c depends only on (tile parity, lg, reg)
  float madd[2][4];
#pragma unroll
  for (int p = 0; p < 2; ++p)
#pragma unroll
    for (int r = 0; r < 4; ++r) {
      int c = p * 16 + lg * 4 + r;
      madd[p][r] = (c >= sj && c <= sj + 6) ? 0.f : -1e30f;
    }

  // Q B-fragments (held in regs, reused across all token tiles)
  s16x4 qf[4];
  const int qrow = row_sel * 32 + j;
#pragma unroll
  for (int ks = 0; ks < 4; ++ks)
    qf[ks] = *(const s16x4*)(sQ + qrow * 64 + ((((ks << 2) + lg) ^ (qrow & 15)) << 2));

  // S^T = K · Q^T
  f32x4 accS[14];
#pragma unroll
  for (int tt = 0; tt < 14; ++tt) {
    f32x4 a = {0.f, 0.f, 0.f, 0.f};
    const int trow = toff + tt * 16 + lm;
    const unsigned short* kr = sK + trow * 64;
    const int sw = trow & 15;
#pragma unroll
    for (int ks = 0; ks < 4; ++ks) {
      s16x4 kf = *(const s16x4*)(kr + ((((ks << 2) + lg) ^ sw) << 2));
      a = __builtin_amdgcn_mfma_f32_16x16x16bf16_1k(kf, qf[ks], a, 0, 0, 0);
    }
    accS[tt] = a;
  }

  // masked softmax (base-2; scale pre-folded into Q)
  float mx = -3e38f;
#pragma unroll
  for (int tt = 0; tt < 14; ++tt)
#pragma unroll
    for (int r = 0; r < 4; ++r) {
      float v = accS[tt][r] + madd[tt & 1][r];
      accS[tt][r] = v;
      mx = fmaxf(mx, v);
    }
  mx = fmaxf(mx, __shfl_xor(mx, 16, 64));
  mx = fmaxf(mx, __shfl_xor(mx, 32, 64));
  float sum = 0.f;
#pragma unroll
  for (int tt = 0; tt < 14; ++tt)
#pragma unroll
    for (int r = 0; r < 4; ++r) {
      float p = exp2f(accS[tt][r] - mx);
      accS[tt][r] = p;
      sum += p;
    }
  sum += __shfl_xor(sum, 16, 64);
  sum += __shfl_xor(sum, 32, 64);
  const float inv = 1.f / sum;

  // P fp32 -> bf16 A-fragments (register-direct, no LDS round-trip)
  s16x4 pf[14];
#pragma unroll
  for (int tt = 0; tt < 14; ++tt) {
    union { unsigned u[2]; s16x4 v; } pk;
    pk.u[0] = ((unsigned)f2bf(accS[tt][1]) << 16) | f2bf(accS[tt][0]);
    pk.u[1] = ((unsigned)f2bf(accS[tt][3]) << 16) | f2bf(accS[tt][2]);
    pf[tt] = pk.v;
  }

  // O = P · V
  f32x4 accO[4] = {};
  const int choff = toff >> 2;
#pragma unroll
  for (int tt = 0; tt < 14; ++tt) {
    const int c8 = choff + tt * 4 + lg;
#pragma unroll
    for (int nt = 0; nt < 4; ++nt) {
      const int d = nt * 16 + lm;
      s16x4 vf = *(const s16x4*)(sVt + d * 256 + ((c8 ^ (d & 15)) << 2));
      accO[nt] = __builtin_amdgcn_mfma_f32_16x16x16bf16_1k(pf[tt], vf, accO[nt], 0, 0, 0);
    }
  }

  // 1/sum per output row (O C-layout row = q = lg*4+reg)
  float invr[4];
#pragma unroll
  for (int r = 0; r < 4; ++r) invr[r] = __shfl(inv, lg * 4 + r, 64);

  const int tokbase = gb + i * 32 + jhalf * 16;
#pragma unroll
  for (int nt = 0; nt < 4; ++nt)
#pragma unroll
    for (int r = 0; r < 4; ++r) {
      int tok = tokbase + lg * 4 + r;
      aout[(size_t)tok * 768 + h * 64 + nt * 16 + lm] = f2bf(accO[nt][r] * invr[r]);
    }
}

// ---------------- launch ----------------
extern "C" void kernel_launch(void* const* d_in, const int* in_sizes, int n_in,
                              void* d_out, int out_size, void* d_ws, size_t ws_size,
                              hipStream_t stream) {
  const float* x      = (const float*)d_in[0];
  const float* qkv_w  = (const float*)d_in[1];
  const float* qkv_b  = (const float*)d_in[2];
  const float* proj_w = (const float*)d_in[3];
  const float* proj_b = (const float*)d_in[4];
  char* ws = (char*)d_ws;

  unsigned short* xb    = (unsigned short*)(ws);                 // 4096*768 bf16
  unsigned short* wqkv  = (unsigned short*)(ws + 6291456);       // 2304*768 bf16
  unsigned short* wproj = (unsigned short*)(ws + 9830400);       // 768*768 bf16
  unsigned short* qkvt  = (unsigned short*)(ws + 11010048);      // Q,K token-major + Vt
  unsigned short* attnb = (unsigned short*)(ws + 29884416);      // 4096*768 bf16
  unsigned short* vt    = qkvt + (size_t)24 * 4096 * 64;         // V transposed [12][64][4096]
  float* out = (float*)d_out;

  cvt_kernel<<<5376, 256, 0, stream>>>(x, qkv_w, proj_w, xb, wqkv, wproj);
  gemm_bt<0, 128, 128><<<dim3(18, 32), 256, 0, stream>>>(xb, wqkv, qkv_b, qkvt, vt, nullptr, 4096, 2304, 768);
  natten_kernel<<<dim3(12, 16, 4), 256, 0, stream>>>(qkvt, attnb);
  gemm_bt<1, 64, 64><<<dim3(12, 64), 256, 0, stream>>>(attnb, wproj, proj_b, nullptr, nullptr, out, 4096, 768, 768);
}

// Round 5
// 135.392 us; speedup vs baseline: 1.1923x; 1.0033x over previous
//
#include <hip/hip_runtime.h>

// B=4, HG=WG=32 -> 1024 tokens/batch, 4096 total; D=768, NH=12, HD=64, K=7 (49 neighbors)

typedef __bf16 bf16x8 __attribute__((ext_vector_type(8)));
typedef short s16x4 __attribute__((ext_vector_type(4)));
typedef float f32x4 __attribute__((ext_vector_type(4)));

__device__ __forceinline__ unsigned short f2bf(float f) {
  unsigned u = __float_as_uint(f);
  u += 0x7fffu + ((u >> 16) & 1u);   // RNE
  return (unsigned short)(u >> 16);
}

template <typename T>
__device__ __forceinline__ void gld_lds16(const T* g, T* l) {
  __builtin_amdgcn_global_load_lds((const __attribute__((address_space(1))) void*)g,
                                   (__attribute__((address_space(3))) void*)l, 16, 0, 0);
}

// ---------------- fp32 -> bf16 conversion of x, qkv_w, proj_w ----------------
__global__ void cvt_kernel(const float* __restrict__ x, const float* __restrict__ w1,
                           const float* __restrict__ w2, unsigned short* __restrict__ xo,
                           unsigned short* __restrict__ w1o, unsigned short* __restrict__ w2o) {
  const int n1 = 4096 * 768 / 4;
  const int n2 = 2304 * 768 / 4;
  const int n3 = 768 * 768 / 4;
  int i = blockIdx.x * 256 + threadIdx.x;
  float4 v;
  unsigned short* dst;
  int o;
  if (i < n1) {
    o = i; v = ((const float4*)x)[o]; dst = xo;
  } else if (i < n1 + n2) {
    o = i - n1; v = ((const float4*)w1)[o]; dst = w1o;
  } else if (i < n1 + n2 + n3) {
    o = i - n1 - n2; v = ((const float4*)w2)[o]; dst = w2o;
  } else {
    return;
  }
  ushort4 r;
  r.x = f2bf(v.x); r.y = f2bf(v.y); r.z = f2bf(v.z); r.w = f2bf(v.w);
  ((ushort4*)dst)[o] = r;
}

// ---------------- bf16 GEMM, C = A * B^T + bias ----------------
// R5: deeper counted-wait pipeline. R4 facts: conflicts=0, FETCH=compulsory,
// yet MfmaUtil pinned at 11% -> pure exposed load latency (per-step ~700cy vs
// 80cy of MFMA). Depth-2 slack was insufficient; this round:
//   MODE 0 (qkv, BM=BN=128): 4 buffers, depth-3, steady wait vmcnt(8)  (64 KB LDS)
//   MODE 1 (proj, BM=BN=64): 5 buffers, depth-4, steady wait vmcnt(6)  (40 KB LDS)
// One raw s_barrier per k-step; buffer rotation race-free (stage of tile k+D
// lands in the buffer last read at step k-1, which the previous barrier fenced).
// XOR chunk swizzle both-sides (rule 21); XCD 2D-rectangle block swizzle.
template <int MODE, int BM, int BN>
__global__ __launch_bounds__(256) void gemm_bt(const unsigned short* __restrict__ A,
                                               const unsigned short* __restrict__ Bm,
                                               const float* __restrict__ bias,
                                               unsigned short* __restrict__ obf,
                                               unsigned short* __restrict__ vtout,
                                               float* __restrict__ of32,
                                               int M, int N, int Kd) {
  constexpr int RA = BM / 64, RB = BN / 64;   // gld rounds per tile (per matrix)
  constexpr int MI = BM / 32, NI = BN / 32;   // 16x16 frags per wave
  constexpr int NB = (MODE == 0) ? 4 : 5;     // LDS buffers
  constexpr int DEPTH = NB - 1;               // tiles in flight ahead
  __shared__ __align__(16) unsigned short sA[NB][BM * 32];
  __shared__ __align__(16) unsigned short sB[NB][BN * 32];
  const int tid = threadIdx.x;
  const int lane = tid & 63;
  const int wv = tid >> 6;

  // XCD rectangles: qkv (18,32): HX=9, HY=8 -> 3.3 MB/XCD. proj (12,64): HX=6, HY=16.
  constexpr int HX = (MODE == 0) ? 9 : 6;
  constexpr int HY = (MODE == 0) ? 8 : 16;
  const int lin = blockIdx.y * gridDim.x + blockIdx.x;
  const int xcd = lin & 7, rrr = lin >> 3;
  const int bx = (xcd & 1) * HX + rrr % HX;
  const int by = (xcd >> 1) * HY + rrr / HX;
  const int m0 = by * BM, n0 = bx * BN;

  const int wrow = (wv >> 1) * (BM / 2), wcol = (wv & 1) * (BN / 2);
  const int lr = lane & 15, lq = lane >> 4;
  // read-side swizzled chunk: physical chunk = lq ^ ((row>>1)&3); row = 16m+lr
  const int rchunk = (lq ^ ((lr >> 1) & 3)) * 8;

  f32x4 acc[MI][NI] = {};

  // source-side chunk swizzle matches read side (both-sides-or-neither).
  const int schunk = ((tid & 3) ^ ((tid >> 3) & 3)) * 8;
  const unsigned short* gA = A + (size_t)(m0 + (tid >> 2)) * Kd + schunk;
  const unsigned short* gB = Bm + (size_t)(n0 + (tid >> 2)) * Kd + schunk;

  const int NS = Kd >> 5;  // 32-wide k-steps (24 here)

#define STAGE_TILE(tile, bufidx)                                                          \
  do {                                                                                    \
    const int _off = (tile) * 32;                                                         \
    unsigned short* _dA = sA[(bufidx)];                                                   \
    unsigned short* _dB = sB[(bufidx)];                                                   \
    _Pragma("unroll")                                                                     \
    for (int _r = 0; _r < RA; ++_r)                                                       \
      gld_lds16(gA + (size_t)(_r * 64) * Kd + _off, _dA + _r * 2048 + tid * 8);           \
    _Pragma("unroll")                                                                     \
    for (int _r = 0; _r < RB; ++_r)                                                       \
      gld_lds16(gB + (size_t)(_r * 64) * Kd + _off, _dB + _r * 2048 + tid * 8);           \
  } while (0)

  // prologue: DEPTH tiles in flight; wait only for tile 0.
#pragma unroll
  for (int t = 0; t < DEPTH; ++t) STAGE_TILE(t, t);
  __builtin_amdgcn_sched_barrier(0);
  if constexpr (MODE == 0) asm volatile("s_waitcnt vmcnt(8) lgkmcnt(0)" ::: "memory");
  else                     asm volatile("s_waitcnt vmcnt(6) lgkmcnt(0)" ::: "memory");
  __builtin_amdgcn_s_barrier();

  int rb = 0, sb = DEPTH;  // read / stage buffer cursors (wrap at NB)
  for (int step = 0; step < NS; ++step) {
    const unsigned short* cA = sA[rb];
    const unsigned short* cB = sB[rb];
    bf16x8 af[MI], bfr[NI];
#pragma unroll
    for (int t = 0; t < MI; ++t) af[t] = *(const bf16x8*)(cA + (wrow + t * 16 + lr) * 32 + rchunk);
#pragma unroll
    for (int t = 0; t < NI; ++t) bfr[t] = *(const bf16x8*)(cB + (wcol + t * 16 + lr) * 32 + rchunk);

    if (step + DEPTH < NS) STAGE_TILE(step + DEPTH, sb);  // issue while MFMAs run

#pragma unroll
    for (int im = 0; im < MI; ++im)
#pragma unroll
      for (int in = 0; in < NI; ++in)
        acc[im][in] = __builtin_amdgcn_mfma_f32_16x16x32_bf16(af[im], bfr[in], acc[im][in], 0, 0, 0);

    __builtin_amdgcn_sched_barrier(0);  // pin stage-issues before the counted wait
    if constexpr (MODE == 0) {
      // L=4/tile: steady 2 tiles in flight after wait
      if (step + 3 < NS)      asm volatile("s_waitcnt vmcnt(8) lgkmcnt(0)" ::: "memory");
      else if (step + 2 < NS) asm volatile("s_waitcnt vmcnt(4) lgkmcnt(0)" ::: "memory");
      else                    asm volatile("s_waitcnt vmcnt(0) lgkmcnt(0)" ::: "memory");
    } else {
      // L=2/tile: steady 3 tiles in flight after wait
      if (step + 4 < NS)      asm volatile("s_waitcnt vmcnt(6) lgkmcnt(0)" ::: "memory");
      else if (step + 3 < NS) asm volatile("s_waitcnt vmcnt(4) lgkmcnt(0)" ::: "memory");
      else if (step + 2 < NS) asm volatile("s_waitcnt vmcnt(2) lgkmcnt(0)" ::: "memory");
      else                    asm volatile("s_waitcnt vmcnt(0) lgkmcnt(0)" ::: "memory");
    }
    __builtin_amdgcn_s_barrier();
    rb = (rb + 1 == NB) ? 0 : rb + 1;
    sb = (sb + 1 == NB) ? 0 : sb + 1;
  }
#undef STAGE_TILE

  if (MODE == 0) {
    const int sidx = n0 / 768;  // block-uniform (768 % BN == 0)
    if (sidx == 2) {
      // V -> transposed vt[(hh*64+dd)*4096 + token]
#pragma unroll
      for (int im = 0; im < MI; ++im) {
#pragma unroll
        for (int in = 0; in < NI; ++in) {
          int gn = n0 + wcol + in * 16 + lr;
          int rem = gn - 1536;
          int hh = rem >> 6, dd = gn & 63;
          float bsv = bias[gn];
          int gm0 = m0 + wrow + im * 16 + lq * 4;
          ushort4 pk;
          pk.x = f2bf(acc[im][in][0] + bsv);
          pk.y = f2bf(acc[im][in][1] + bsv);
          pk.z = f2bf(acc[im][in][2] + bsv);
          pk.w = f2bf(acc[im][in][3] + bsv);
          *(ushort4*)(vtout + (size_t)(hh * 64 + dd) * 4096 + gm0) = pk;
        }
      }
    } else {
      const float scale = (sidx == 0) ? 0.18033688f : 1.0f;  // 0.125 * log2(e) for Q
#pragma unroll
      for (int im = 0; im < MI; ++im) {
#pragma unroll
        for (int in = 0; in < NI; ++in) {
          int gn = n0 + wcol + in * 16 + lr;
          int rem = gn - sidx * 768;
          int hh = rem >> 6, dd = gn & 63;
          float bsv = bias[gn];
#pragma unroll
          for (int r = 0; r < 4; ++r) {
            int gm = m0 + wrow + im * 16 + lq * 4 + r;
            float val = (acc[im][in][r] + bsv) * scale;
            obf[((size_t)(sidx * 12 + hh) * 4096 + gm) * 64 + dd] = f2bf(val);
          }
        }
      }
    }
  } else {
#pragma unroll
    for (int im = 0; im < MI; ++im) {
#pragma unroll
      for (int in = 0; in < NI; ++in) {
        int gn = n0 + wcol + in * 16 + lr;
        float bsv = bias[gn];
#pragma unroll
        for (int r = 0; r < 4; ++r) {
          int gm = m0 + wrow + im * 16 + lq * 4 + r;
          of32[(size_t)gm * N + gn] = acc[im][in][r] + bsv;
        }
      }
    }
  }
}

// ---------------- neighborhood attention (MFMA) ----------------
// Proven R0/R1 version (72 KB LDS, 2 blocks/CU) — frozen this round.
// Block = (head, query-row-pair, batch): 64 queries, stages 8 KV grid rows (256 tok).
// S^T = K·Q^T via mfma_16x16x16_bf16: C-layout (col=lane&15=q, row=lg*4+reg=t) is
// EXACTLY the A-operand layout of PV -> P stays in registers.
__global__ __launch_bounds__(256, 2) void natten_kernel(const unsigned short* __restrict__ qkvt,
                                                        unsigned short* __restrict__ aout) {
  __shared__ __align__(16) unsigned short sQ[64 * 64];    //  8 KB
  __shared__ __align__(16) unsigned short sK[256 * 64];   // 32 KB
  __shared__ __align__(16) unsigned short sVt[64 * 256];  // 32 KB
  const int h = blockIdx.x, ip = blockIdx.y, b = blockIdx.z;
  const int i0 = ip * 2;
  const int tid = threadIdx.x, lane = tid & 63, wv = tid >> 6;
  const int lg = lane >> 4, lm = lane & 15;
  int si0 = i0 - 3; si0 = si0 < 0 ? 0 : si0; if (si0 > 25) si0 = 25;
  const int gb = b * 1024;
  const unsigned short* Qg = qkvt + ((size_t)h * 4096 + gb + i0 * 32) * 64;
  const unsigned short* Kg = qkvt + ((size_t)(12 + h) * 4096 + gb) * 64;
  const unsigned short* Vg = qkvt + (size_t)24 * 4096 * 64 + (size_t)h * 64 * 4096 + gb;

  // ---- staging (16B global loads, two 8B LDS writes w/ 4-bit XOR chunk swizzle) ----
#pragma unroll
  for (int it = 0; it < 2; ++it) {  // Q: 64 q x 64 d
    int f = it * 256 + tid;
    int q = f >> 3, c16 = f & 7;
    uint4 v = *(const uint4*)(Qg + q * 64 + c16 * 8);
    int s = q & 15;
    *(uint2*)(sQ + q * 64 + ((((c16 << 1)) ^ s) << 2)) = make_uint2(v.x, v.y);
    *(uint2*)(sQ + q * 64 + ((((c16 << 1) | 1) ^ s) << 2)) = make_uint2(v.z, v.w);
  }
#pragma unroll
  for (int it = 0; it < 8; ++it) {  // K: 256 tok x 64 d
    int f = it * 256 + tid;
    int t = f >> 3, c16 = f & 7;
    int wr = t >> 5, c = t & 31;
    int row = si0 + wr; if (row > 31) row = 31;
    uint4 v = *(const uint4*)(Kg + (row * 32 + c) * 64 + c16 * 8);
    int s = t & 15;
    *(uint2*)(sK + t * 64 + ((((c16 << 1)) ^ s) << 2)) = make_uint2(v.x, v.y);
    *(uint2*)(sK + t * 64 + ((((c16 << 1) | 1) ^ s) << 2)) = make_uint2(v.z, v.w);
  }
#pragma unroll
  for (int it = 0; it < 8; ++it) {  // Vt: 64 d x 256 tok
    int f = it * 256 + tid;
    int d = f >> 5, tc16 = f & 31;
    int wr = tc16 >> 2;
    int row = si0 + wr; if (row > 31) row = 31;
    uint4 v = *(const uint4*)(Vg + (size_t)d * 4096 + row * 32 + (tc16 & 3) * 8);
    int s = d & 15;
    *(uint2*)(sVt + d * 256 + ((((tc16 << 1)) ^ s) << 2)) = make_uint2(v.x, v.y);
    *(uint2*)(sVt + d * 256 + ((((tc16 << 1) | 1) ^ s) << 2)) = make_uint2(v.z, v.w);
  }
  __syncthreads();

  const int row_sel = wv >> 1;
  const int jhalf = wv & 1;
  const int i = i0 + row_sel;
  int si_w = i - 3; si_w = si_w < 0 ? 0 : si_w; if (si_w > 25) si_w = 25;
  const int toff = (si_w - si0) * 32;
  const int j = jhalf * 16 + lm;
  int sj = j - 3; sj = sj < 0 ? 0 : sj; if (sj > 25) sj = 25;

  // column mask: token col c depends only on (tile parity, lg, reg)
  float madd[2][4];
#pragma unroll
  for (int p = 0; p < 2; ++p)
#pragma unroll
    for (int r = 0; r < 4; ++r) {
      int c = p * 16 + lg * 4 + r;
      madd[p][r] = (c >= sj && c <= sj + 6) ? 0.f : -1e30f;
    }

  // Q B-fragments (held in regs, reused across all token tiles)
  s16x4 qf[4];
  const int qrow = row_sel * 32 + j;
#pragma unroll
  for (int ks = 0; ks < 4; ++ks)
    qf[ks] = *(const s16x4*)(sQ + qrow * 64 + ((((ks << 2) + lg) ^ (qrow & 15)) << 2));

  // S^T = K · Q^T
  f32x4 accS[14];
#pragma unroll
  for (int tt = 0; tt < 14; ++tt) {
    f32x4 a = {0.f, 0.f, 0.f, 0.f};
    const int trow = toff + tt * 16 + lm;
    const unsigned short* kr = sK + trow * 64;
    const int sw = trow & 15;
#pragma unroll
    for (int ks = 0; ks < 4; ++ks) {
      s16x4 kf = *(const s16x4*)(kr + ((((ks << 2) + lg) ^ sw) << 2));
      a = __builtin_amdgcn_mfma_f32_16x16x16bf16_1k(kf, qf[ks], a, 0, 0, 0);
    }
    accS[tt] = a;
  }

  // masked softmax (base-2; scale pre-folded into Q)
  float mx = -3e38f;
#pragma unroll
  for (int tt = 0; tt < 14; ++tt)
#pragma unroll
    for (int r = 0; r < 4; ++r) {
      float v = accS[tt][r] + madd[tt & 1][r];
      accS[tt][r] = v;
      mx = fmaxf(mx, v);
    }
  mx = fmaxf(mx, __shfl_xor(mx, 16, 64));
  mx = fmaxf(mx, __shfl_xor(mx, 32, 64));
  float sum = 0.f;
#pragma unroll
  for (int tt = 0; tt < 14; ++tt)
#pragma unroll
    for (int r = 0; r < 4; ++r) {
      float p = exp2f(accS[tt][r] - mx);
      accS[tt][r] = p;
      sum += p;
    }
  sum += __shfl_xor(sum, 16, 64);
  sum += __shfl_xor(sum, 32, 64);
  const float inv = 1.f / sum;

  // P fp32 -> bf16 A-fragments (register-direct, no LDS round-trip)
  s16x4 pf[14];
#pragma unroll
  for (int tt = 0; tt < 14; ++tt) {
    union { unsigned u[2]; s16x4 v; } pk;
    pk.u[0] = ((unsigned)f2bf(accS[tt][1]) << 16) | f2bf(accS[tt][0]);
    pk.u[1] = ((unsigned)f2bf(accS[tt][3]) << 16) | f2bf(accS[tt][2]);
    pf[tt] = pk.v;
  }

  // O = P · V
  f32x4 accO[4] = {};
  const int choff = toff >> 2;
#pragma unroll
  for (int tt = 0; tt < 14; ++tt) {
    const int c8 = choff + tt * 4 + lg;
#pragma unroll
    for (int nt = 0; nt < 4; ++nt) {
      const int d = nt * 16 + lm;
      s16x4 vf = *(const s16x4*)(sVt + d * 256 + ((c8 ^ (d & 15)) << 2));
      accO[nt] = __builtin_amdgcn_mfma_f32_16x16x16bf16_1k(pf[tt], vf, accO[nt], 0, 0, 0);
    }
  }

  // 1/sum per output row (O C-layout row = q = lg*4+reg)
  float invr[4];
#pragma unroll
  for (int r = 0; r < 4; ++r) invr[r] = __shfl(inv, lg * 4 + r, 64);

  const int tokbase = gb + i * 32 + jhalf * 16;
#pragma unroll
  for (int nt = 0; nt < 4; ++nt)
#pragma unroll
    for (int r = 0; r < 4; ++r) {
      int tok = tokbase + lg * 4 + r;
      aout[(size_t)tok * 768 + h * 64 + nt * 16 + lm] = f2bf(accO[nt][r] * invr[r]);
    }
}

// ---------------- launch ----------------
extern "C" void kernel_launch(void* const* d_in, const int* in_sizes, int n_in,
                              void* d_out, int out_size, void* d_ws, size_t ws_size,
                              hipStream_t stream) {
  const float* x      = (const float*)d_in[0];
  const float* qkv_w  = (const float*)d_in[1];
  const float* qkv_b  = (const float*)d_in[2];
  const float* proj_w = (const float*)d_in[3];
  const float* proj_b = (const float*)d_in[4];
  char* ws = (char*)d_ws;

  unsigned short* xb    = (unsigned short*)(ws);                 // 4096*768 bf16
  unsigned short* wqkv  = (unsigned short*)(ws + 6291456);       // 2304*768 bf16
  unsigned short* wproj = (unsigned short*)(ws + 9830400);       // 768*768 bf16
  unsigned short* qkvt  = (unsigned short*)(ws + 11010048);      // Q,K token-major + Vt
  unsigned short* attnb = (unsigned short*)(ws + 29884416);      // 4096*768 bf16
  unsigned short* vt    = qkvt + (size_t)24 * 4096 * 64;         // V transposed [12][64][4096]
  float* out = (float*)d_out;

  cvt_kernel<<<5376, 256, 0, stream>>>(x, qkv_w, proj_w, xb, wqkv, wproj);
  gemm_bt<0, 128, 128><<<dim3(18, 32), 256, 0, stream>>>(xb, wqkv, qkv_b, qkvt, vt, nullptr, 4096, 2304, 768);
  natten_kernel<<<dim3(12, 16, 4), 256, 0, stream>>>(qkvt, attnb);
  gemm_bt<1, 64, 64><<<dim3(12, 64), 256, 0, stream>>>(attnb, wproj, proj_b, nullptr, nullptr, out, 4096, 768, 768);
}